// Round 1
// baseline (652.355 us; speedup 1.0000x reference)
//
#include <hip/hip_runtime.h>

// out[b] = sum_{i} x[b,i] * |W[i]| * fc1_w[i] + fc1_b ; B=32, N = T*P = 4e6.
// Strategy: each (block.x, group) computes s = |W|*fc1_w once in registers and
// reuses it for 8 batch rows -> every x byte crosses HBM exactly once
// (~544 MB total => ~86 us floor at 6.3 TB/s).
// This round: x loads are non-temporal (pure stream, zero reuse) so the 32 MB
// of W/fc1_w (re-read by all 4 batch groups) stays L2/L3-resident.
#define BATCH 32
#define NELEM 4000000
#define N4 (NELEM / 4)     // 1,000,000 float4 per batch row
#define BLK 256
#define BPG 8              // batch rows per group
#define GROUPS (BATCH / BPG)
#define NBLK 512           // blocks per group -> 2048 blocks total (8/CU)

typedef float f4 __attribute__((ext_vector_type(4)));

__global__ __launch_bounds__(BLK)
void stage1_kernel(const f4* __restrict__ x,       // [BATCH][N4]
                   const f4* __restrict__ W,       // [N4]
                   const f4* __restrict__ F,       // [N4]
                   float* __restrict__ partials) { // [BATCH][NBLK]
    const int g  = blockIdx.y;                     // batch group 0..GROUPS-1
    const int bx = blockIdx.x;                     // 0..NBLK-1
    const f4* __restrict__ xg = x + (size_t)g * BPG * N4;

    float acc[BPG];
    #pragma unroll
    for (int r = 0; r < BPG; ++r) acc[r] = 0.0f;

    const int stride = NBLK * BLK;
    for (int i = bx * BLK + threadIdx.x; i < N4; i += stride) {
        f4 wv = W[i];        // cached: reused by all 4 batch groups
        f4 fv = F[i];
        f4 s;
        s.x = fabsf(wv.x) * fv.x;
        s.y = fabsf(wv.y) * fv.y;
        s.z = fabsf(wv.z) * fv.z;
        s.w = fabsf(wv.w) * fv.w;
        const f4* __restrict__ xp = xg + i;
        #pragma unroll
        for (int r = 0; r < BPG; ++r) {
            f4 xv = __builtin_nontemporal_load(xp + (size_t)r * N4);  // stream
            acc[r] += xv.x * s.x + xv.y * s.y + xv.z * s.z + xv.w * s.w;
        }
    }

    // Wave-64 shuffle reduction for each of the 8 accumulators.
    #pragma unroll
    for (int r = 0; r < BPG; ++r) {
        #pragma unroll
        for (int off = 32; off > 0; off >>= 1)
            acc[r] += __shfl_down(acc[r], off, 64);
    }

    __shared__ float lds[BLK / 64][BPG];
    const int lane = threadIdx.x & 63;
    const int wv   = threadIdx.x >> 6;
    if (lane == 0) {
        #pragma unroll
        for (int r = 0; r < BPG; ++r) lds[wv][r] = acc[r];
    }
    __syncthreads();

    if (threadIdx.x < BPG) {
        const int r = threadIdx.x;
        float t = lds[0][r] + lds[1][r] + lds[2][r] + lds[3][r];
        partials[(size_t)(g * BPG + r) * NBLK + bx] = t;
    }
}

__global__ __launch_bounds__(64)
void stage2_kernel(const float* __restrict__ partials, // [BATCH][NBLK]
                   const float* __restrict__ fc1_b,
                   float* __restrict__ out) {          // [BATCH]
    const int b    = blockIdx.x;   // 0..BATCH-1
    const int lane = threadIdx.x;  // 0..63
    float t = 0.0f;
    #pragma unroll
    for (int k = lane; k < NBLK; k += 64) t += partials[(size_t)b * NBLK + k];
    #pragma unroll
    for (int off = 32; off > 0; off >>= 1) t += __shfl_down(t, off, 64);
    if (lane == 0) out[b] = t + fc1_b[0];
}

extern "C" void kernel_launch(void* const* d_in, const int* in_sizes, int n_in,
                              void* d_out, int out_size, void* d_ws, size_t ws_size,
                              hipStream_t stream) {
    const float* x     = (const float*)d_in[0];  // [B, T, P]
    const float* W     = (const float*)d_in[1];  // [T, P]
    const float* fc1_w = (const float*)d_in[2];  // [1, T*P]
    const float* fc1_b = (const float*)d_in[3];  // [1]
    float* out      = (float*)d_out;             // [B, 1]
    float* partials = (float*)d_ws;              // BATCH*NBLK floats (64 KB)

    dim3 grid(NBLK, GROUPS);
    stage1_kernel<<<grid, BLK, 0, stream>>>(
        (const f4*)x, (const f4*)W, (const f4*)fc1_w, partials);
    stage2_kernel<<<BATCH, 64, 0, stream>>>(partials, fc1_b, out);
}